// Round 20
// baseline (179.038 us; speedup 1.0000x reference)
//
#include <hip/hip_runtime.h>
#include <hip/hip_bf16.h>

#define NROWS 8192
#define DIM 512
#define BM 256
#define BN 256

typedef int   i32x4 __attribute__((ext_vector_type(4)));
typedef int   i32x8 __attribute__((ext_vector_type(8)));
typedef float f32x4 __attribute__((ext_vector_type(4)));

#define FP8_SCALE_1 0x7f7f7f7f   // E8M0 127 = 2^0 in all 4 bytes

__device__ __forceinline__ void gld_lds16(const void* g, void* l) {
  __builtin_amdgcn_global_load_lds(
      (__attribute__((address_space(1))) unsigned int*)(g),
      (__attribute__((address_space(3))) unsigned int*)(l),
      16, 0, 0);
}

// ---------- Phase 1: normalize rows -> fp8 e4m3; diag logits in fp32 ----------
__global__ __launch_bounds__(128) void prep_k(
    const float* __restrict__ q, const float* __restrict__ p,
    unsigned int* __restrict__ qh, unsigned int* __restrict__ ph,
    float* __restrict__ diag) {
  const int i = blockIdx.x;
  const int t = threadIdx.x;
  const int lane = t & 63, wid = t >> 6;
  const float4 qv = ((const float4*)(q + (size_t)i * DIM))[t];
  const float4 pv = ((const float4*)(p + (size_t)i * DIM))[t];
  float ssq = qv.x*qv.x + qv.y*qv.y + qv.z*qv.z + qv.w*qv.w;
  float ssp = pv.x*pv.x + pv.y*pv.y + pv.z*pv.z + pv.w*pv.w;
  float dt  = qv.x*pv.x + qv.y*pv.y + qv.z*pv.z + qv.w*pv.w;
  #pragma unroll
  for (int m = 1; m < 64; m <<= 1) {
    ssq += __shfl_xor(ssq, m, 64);
    ssp += __shfl_xor(ssp, m, 64);
    dt  += __shfl_xor(dt,  m, 64);
  }
  __shared__ float red[3][2];
  if (lane == 0) { red[0][wid] = ssq; red[1][wid] = ssp; red[2][wid] = dt; }
  __syncthreads();
  ssq = red[0][0] + red[0][1];
  ssp = red[1][0] + red[1][1];
  dt  = red[2][0] + red[2][1];
  const float invq = 1.0f / fmaxf(sqrtf(ssq), 1e-8f);
  const float invp = 1.0f / fmaxf(sqrtf(ssp), 1e-8f);
  int rq = 0, rp = 0;
  rq = __builtin_amdgcn_cvt_pk_fp8_f32(qv.x * invq, qv.y * invq, rq, false);
  rq = __builtin_amdgcn_cvt_pk_fp8_f32(qv.z * invq, qv.w * invq, rq, true);
  rp = __builtin_amdgcn_cvt_pk_fp8_f32(pv.x * invp, pv.y * invp, rp, false);
  rp = __builtin_amdgcn_cvt_pk_fp8_f32(pv.z * invp, pv.w * invp, rp, true);
  qh[i * 128 + t] = (unsigned int)rq;
  ph[i * 128 + t] = (unsigned int)rp;
  if (t == 0) diag[i] = dt * invq * invp * 20.0f;
}

// ---------- Phase 2: MX-fp8 GEMM, 4 FAT waves (128x128/wave), 1 wave/SIMD ----------
// 256 persistent blocks (1/CU), 256 thr = 4 waves (2x2 of 128x128). LDS-read
// conservation: reads/iter = K*(BM*multA + BN*multB); fat waves cut mult from
// (4A,2B) to (2A,2B): 192KB -> 128KB/iter, the dominant pipe (2300->1536cy vs
// MFMA 550cy). VGPR: acc 256 + operands 128 + temps ~40 = ~420, legal ONLY at
// 1 wave/SIMD (512 budget) -> __launch_bounds__(256,1). A single wave keeps
// both pipes full via in-order non-blocking issue (reads stream under MFMAs).
// Everything else = r15 champion: L2-resident XCD map, XOR swizzle, transposed
// accumulators (lane holds row m=l15 fixed), 1 vmcnt(0)+barrier per iter.
// SPILL TRIPWIRE: if WRITE_SIZE balloons (r8/r11 signature), revert.
__device__ __forceinline__ i32x8 rd32(const char* base, int c0, int sw) {
  const i32x4 lo = *(const i32x4*)(base + ((c0     ) ^ sw));
  const i32x4 hi = *(const i32x4*)(base + ((c0 + 16) ^ sw));
  return __builtin_shufflevector(lo, hi, 0, 1, 2, 3, 4, 5, 6, 7);
}
// stage one 256-row x 128B operand (8 gld_lds per thread, 256 threads)
__device__ __forceinline__ void stage_op(const char* __restrict__ g, char* dstb,
                                         int rowbase, int tid, int kb) {
  #pragma unroll
  for (int jj = 0; jj < 8; ++jj) {
    const int idx = jj * 256 + tid;
    const int rl = idx >> 3;
    const int scb = ((idx & 7) << 4) ^ ((rl & 7) << 4);
    gld_lds16(g + (size_t)(rowbase + rl) * 512 + kb + scb, dstb + idx * 16);
  }
}

__global__ __launch_bounds__(256, 1) void gemm_lse_k(
    const unsigned int* __restrict__ qh, const unsigned int* __restrict__ ph,
    float* __restrict__ partial) {
  __shared__ __attribute__((aligned(16))) char lds[133120];  // 2x64KB dbuf + 2KB psum
  const int tid = threadIdx.x;
  const int lane = tid & 63, wid = tid >> 6;
  const int wr = wid >> 1, wc = wid & 1;        // 2x2 wave grid, 128x128 each
  const int l15 = lane & 15, l4 = lane >> 4;
  const int sw = (l15 & 7) << 4;
  const int c0 = l4 * 32;
  const int b = blockIdx.x;
  const int g = b & 7;                          // XCD (round-robin dispatch)
  const int j = b >> 3;                         // 0..31 within XCD
  const int bm = ((g & 3) * 8 + (j & 7)) * BM;         // A panel (4 blocks share)
  const int bnset = (g >> 2) * 16 + (j >> 3) * 4;      // 4 bn panels (8 share)
  const char* qh8 = (const char*)qh;
  const char* ph8 = (const char*)ph;
  float* psum = (float*)(lds + 131072);         // [2][256] by col-half
  const int aOff = (wr * 128 + l15) * 128;      // + mf*2048
  const int bOff = 32768 + (wc * 128 + l15) * 128;     // + nf*2048

  f32x4 acc[8][8] = {};                         // [nb][am], transposed (256 VGPR)
  i32x8 af[8], bf[8];                           // 128 VGPR

  // Prologue: stage tile 0 (bn = bnset, k-tile 0), drain, barrier.
  stage_op(qh8, lds, bm, tid, 0);
  stage_op(ph8, lds + 32768, bnset * BN, tid, 0);
  asm volatile("s_waitcnt vmcnt(0)" ::: "memory");
  __builtin_amdgcn_s_barrier();

  #pragma unroll 1
  for (int tt = 0; tt < 16; ++tt) {
    const char* rb = lds + (tt & 1) * 65536;
    char* sb = lds + ((tt + 1) & 1) * 65536;
    const int ttn = tt + 1;
    const int kbn = (ttn & 3) * 128;                     // next K-tile byte offset
    const int bnn = (bnset + ((ttn >> 2) & 3)) * BN;     // next tile's bn

    // front-load all 32 ds_read_b128 for this K-iter
    #pragma unroll
    for (int mf = 0; mf < 8; ++mf)
      af[mf] = rd32(rb + aOff + mf * 2048, c0, sw);
    #pragma unroll
    for (int nf = 0; nf < 8; ++nf)
      bf[nf] = rd32(rb + bOff + nf * 2048, c0, sw);
    if (tt < 15) {
      stage_op(qh8, sb, bm, tid, kbn);
      stage_op(ph8, sb + 32768, bnn, tid, kbn);
    }
    __builtin_amdgcn_s_setprio(1);
    #pragma unroll
    for (int nb = 0; nb < 8; ++nb)
      #pragma unroll
      for (int am = 0; am < 8; ++am)
        acc[nb][am] = __builtin_amdgcn_mfma_scale_f32_16x16x128_f8f6f4(
            bf[nb], af[am], acc[nb][am], 0, 0, 0, FP8_SCALE_1, 0, FP8_SCALE_1);
    __builtin_amdgcn_s_setprio(0);
    asm volatile("s_waitcnt vmcnt(0)" ::: "memory");  // stages issued early
    __builtin_amdgcn_s_barrier();

    if ((tt & 3) == 3) {
      // ---- flush output tile (tt>>2): exp(20c-20) + row-sum + store ----
      // Lane rows m = wr*128 + am*16 + l15; cols n = wc*128 + nb*16 + l4*4 + r.
      const int bxc = bnset + (tt >> 2);
      #pragma unroll
      for (int am = 0; am < 8; ++am) {
        float s = 0.0f;
        #pragma unroll
        for (int nb = 0; nb < 8; ++nb)
          #pragma unroll
          for (int r = 0; r < 4; ++r)
            s += __expf(acc[nb][am][r] * 20.0f - 20.0f);
        s += __shfl_xor(s, 16, 64);
        s += __shfl_xor(s, 32, 64);
        if (l4 == 0)
          psum[wc * 256 + wr * 128 + am * 16 + l15] = s;
      }
      asm volatile("s_waitcnt lgkmcnt(0)" ::: "memory");
      __builtin_amdgcn_s_barrier();
      if (tid < 256) {
        float s = psum[tid] + psum[256 + tid];
        partial[(size_t)(bm + tid) * 32 + bxc] = s;
      }
      #pragma unroll
      for (int nb = 0; nb < 8; ++nb)
        #pragma unroll
        for (int am = 0; am < 8; ++am)
          acc[nb][am] = f32x4{0.0f, 0.0f, 0.0f, 0.0f};
    }
  }
}

// ---------- Phase 3a: per-row loss ----------
__global__ __launch_bounds__(256) void rowloss_k(
    const float* __restrict__ partial, const float* __restrict__ diag,
    float* __restrict__ rowloss) {
  const int i = blockIdx.x * 256 + threadIdx.x;
  const float4* pr = (const float4*)(partial + (size_t)i * 32);
  float s = 0.0f;
  #pragma unroll
  for (int c = 0; c < 8; ++c) {
    const float4 v = pr[c];
    s += v.x + v.y + v.z + v.w;
  }
  rowloss[i] = __logf(s) + 20.0f - diag[i];
}

// ---------- Phase 3b: mean ----------
__global__ __launch_bounds__(1024) void final_k(
    const float* __restrict__ rowloss, float* __restrict__ out) {
  const int t = threadIdx.x;
  float s = 0.0f;
  #pragma unroll
  for (int j = 0; j < 8; ++j) s += rowloss[t + j * 1024];
  #pragma unroll
  for (int m = 1; m < 64; m <<= 1) s += __shfl_xor(s, m, 64);
  __shared__ float red[16];
  if ((t & 63) == 0) red[t >> 6] = s;
  __syncthreads();
  if (t == 0) {
    float acc = 0.0f;
    #pragma unroll
    for (int w = 0; w < 16; ++w) acc += red[w];
    out[0] = acc * (1.0f / (float)NROWS);
  }
}

extern "C" void kernel_launch(void* const* d_in, const int* in_sizes, int n_in,
                              void* d_out, int out_size, void* d_ws, size_t ws_size,
                              hipStream_t stream) {
  const float* q = (const float*)d_in[0];
  const float* p = (const float*)d_in[1];
  char* w = (char*)d_ws;
  unsigned int* qh = (unsigned int*)w;                        // 4 MB fp8
  unsigned int* ph = (unsigned int*)(w + 4194304);            // 4 MB fp8
  float* partial    = (float*)(w + 8388608);                  // 1 MB [8192][32]
  float* diag       = (float*)(w + 9437184);                  // 32 KB
  float* rowloss    = (float*)(w + 9437184 + 32768);          // 32 KB
  float* out = (float*)d_out;

  prep_k<<<NROWS, 128, 0, stream>>>(q, p, qh, ph, diag);
  gemm_lse_k<<<256, 256, 0, stream>>>(qh, ph, partial);
  rowloss_k<<<NROWS / 256, 256, 0, stream>>>(partial, diag, rowloss);
  final_k<<<1, 1024, 0, stream>>>(rowloss, out);
}

// Round 21
// 112.469 us; speedup vs baseline: 1.5919x; 1.5919x over previous
//
#include <hip/hip_runtime.h>
#include <hip/hip_bf16.h>

#define NROWS 8192
#define DIM 512
#define BM 256
#define BN 256

typedef int   i32x4 __attribute__((ext_vector_type(4)));
typedef int   i32x8 __attribute__((ext_vector_type(8)));
typedef float f32x4 __attribute__((ext_vector_type(4)));

#define FP8_SCALE_1 0x7f7f7f7f   // E8M0 127 = 2^0 in all 4 bytes

// ---------- Phase 1: normalize rows -> fp8 e4m3; diag logits in fp32 ----------
__global__ __launch_bounds__(128) void prep_k(
    const float* __restrict__ q, const float* __restrict__ p,
    unsigned int* __restrict__ qh, unsigned int* __restrict__ ph,
    float* __restrict__ diag) {
  const int i = blockIdx.x;
  const int t = threadIdx.x;
  const int lane = t & 63, wid = t >> 6;
  const float4 qv = ((const float4*)(q + (size_t)i * DIM))[t];
  const float4 pv = ((const float4*)(p + (size_t)i * DIM))[t];
  float ssq = qv.x*qv.x + qv.y*qv.y + qv.z*qv.z + qv.w*qv.w;
  float ssp = pv.x*pv.x + pv.y*pv.y + pv.z*pv.z + pv.w*pv.w;
  float dt  = qv.x*pv.x + qv.y*pv.y + qv.z*pv.z + qv.w*pv.w;
  #pragma unroll
  for (int m = 1; m < 64; m <<= 1) {
    ssq += __shfl_xor(ssq, m, 64);
    ssp += __shfl_xor(ssp, m, 64);
    dt  += __shfl_xor(dt,  m, 64);
  }
  __shared__ float red[3][2];
  if (lane == 0) { red[0][wid] = ssq; red[1][wid] = ssp; red[2][wid] = dt; }
  __syncthreads();
  ssq = red[0][0] + red[0][1];
  ssp = red[1][0] + red[1][1];
  dt  = red[2][0] + red[2][1];
  const float invq = 1.0f / fmaxf(sqrtf(ssq), 1e-8f);
  const float invp = 1.0f / fmaxf(sqrtf(ssp), 1e-8f);
  int rq = 0, rp = 0;
  rq = __builtin_amdgcn_cvt_pk_fp8_f32(qv.x * invq, qv.y * invq, rq, false);
  rq = __builtin_amdgcn_cvt_pk_fp8_f32(qv.z * invq, qv.w * invq, rq, true);
  rp = __builtin_amdgcn_cvt_pk_fp8_f32(pv.x * invp, pv.y * invp, rp, false);
  rp = __builtin_amdgcn_cvt_pk_fp8_f32(pv.z * invp, pv.w * invp, rp, true);
  qh[i * 128 + t] = (unsigned int)rq;
  ph[i * 128 + t] = (unsigned int)rp;
  if (t == 0) diag[i] = dt * invq * invp * 20.0f;
}

// ---------- Phase 2: MX-fp8 GEMM, DIRECT global->register fragments ----------
// No LDS operand staging at all. Rationale: r13 proved panels are L2-resident
// (FETCH 12.6MB, 3MB/XCD map) -> every fragment load is an L1/L2 hit. This
// removes the LDS pipe (2304 cyc reads + 512 cyc writes per iter — the wall
// five schedules failed to overlap) AND all K-loop barriers: waves run fully
// desynchronized, compiler emits counted vmcnt per dependency, next iter's
// loads issue while current MFMAs drain (in-order overlap for free).
// 256 persistent blocks (1/CU), 8 waves (2Mx4N), 128x64 out/wave, transposed
// accumulators (lane holds row m=l15 fixed -> 2-shuffle row-sum). Fragment
// addressing: frag lo/hi 16B pairs are in the SAME 128B line per row (l4*32
// within the row's 128B kt-window) -> full-sector L2 accesses.
__device__ __forceinline__ i32x8 ldg32(const char* gp) {
  const i32x4 lo = *(const i32x4*)(gp);
  const i32x4 hi = *(const i32x4*)(gp + 16);
  return __builtin_shufflevector(lo, hi, 0, 1, 2, 3, 4, 5, 6, 7);
}

__global__ __launch_bounds__(512, 2) void gemm_lse_k(
    const unsigned int* __restrict__ qh, const unsigned int* __restrict__ ph,
    float* __restrict__ partial) {
  __shared__ float psum[1024];                  // only LDS use: 4KB flush buffer
  const int tid = threadIdx.x;
  const int lane = tid & 63, wid = tid >> 6;
  const int wr = wid >> 2, wc = wid & 3;        // 2M x 4N wave grid
  const int l15 = lane & 15, l4 = lane >> 4;
  const int b = blockIdx.x;
  const int g = b & 7;                          // XCD (round-robin dispatch)
  const int j = b >> 3;                         // 0..31 within XCD
  const int bm = ((g & 3) * 8 + (j & 7)) * BM;         // A panel (4 blocks share)
  const int bnset = (g >> 2) * 16 + (j >> 3) * 4;      // 4 bn panels (8 share)
  const char* qh8 = (const char*)qh;
  const char* ph8 = (const char*)ph;

  // Per-lane fragment bases. A frag mf: +mf*16*512, kt: +kt*128.
  const char* aBase = qh8 + (size_t)(bm + wr * 128 + l15) * 512 + l4 * 32;
  const char* bBase = ph8 + (size_t)(wc * 64 + l15) * 512 + l4 * 32;

  f32x4 acc[4][8] = {};                         // [nb][am], transposed
  i32x8 af[8], bf[4];

  #pragma unroll 1
  for (int tt = 0; tt < 16; ++tt) {
    const int kt = tt & 3, t = tt >> 2;
    const char* aP = aBase + kt * 128;
    const char* bP = bBase + (size_t)(bnset + t) * BN * 512 + kt * 128;

    // 24 global loads (L2-hot); order so MFMA n-batches unlock progressively
    bf[0] = ldg32(bP);
    #pragma unroll
    for (int mf = 0; mf < 8; ++mf)
      af[mf] = ldg32(aP + mf * 8192);           // 16 rows x 512B
    #pragma unroll
    for (int nf = 1; nf < 4; ++nf)
      bf[nf] = ldg32(bP + nf * 8192);

    __builtin_amdgcn_s_setprio(1);
    #pragma unroll
    for (int nb = 0; nb < 4; ++nb)
      #pragma unroll
      for (int am = 0; am < 8; ++am)
        acc[nb][am] = __builtin_amdgcn_mfma_scale_f32_16x16x128_f8f6f4(
            bf[nb], af[am], acc[nb][am], 0, 0, 0, FP8_SCALE_1, 0, FP8_SCALE_1);
    __builtin_amdgcn_s_setprio(0);

    if ((tt & 3) == 3) {
      // ---- flush output tile t: exp(20c-20) + row-sum + store ----
      // Lane rows m = wr*128 + am*16 + l15; cols n = wc*64 + nb*16 + l4*4 + r.
      const int bxc = bnset + t;
      #pragma unroll
      for (int am = 0; am < 8; ++am) {
        float s = 0.0f;
        #pragma unroll
        for (int nb = 0; nb < 4; ++nb)
          #pragma unroll
          for (int r = 0; r < 4; ++r)
            s += __expf(acc[nb][am][r] * 20.0f - 20.0f);
        s += __shfl_xor(s, 16, 64);
        s += __shfl_xor(s, 32, 64);
        if (l4 == 0)
          psum[wc * 256 + wr * 128 + am * 16 + l15] = s;
      }
      __syncthreads();
      if (tid < 256)
        partial[(size_t)(bm + tid) * 32 + bxc] =
            psum[tid] + psum[256 + tid] + psum[512 + tid] + psum[768 + tid];
      __syncthreads();      // psum safe before next tile's writes
      #pragma unroll
      for (int nb = 0; nb < 4; ++nb)
        #pragma unroll
        for (int am = 0; am < 8; ++am)
          acc[nb][am] = f32x4{0.0f, 0.0f, 0.0f, 0.0f};
    }
  }
}

// ---------- Phase 3a: per-row loss ----------
__global__ __launch_bounds__(256) void rowloss_k(
    const float* __restrict__ partial, const float* __restrict__ diag,
    float* __restrict__ rowloss) {
  const int i = blockIdx.x * 256 + threadIdx.x;
  const float4* pr = (const float4*)(partial + (size_t)i * 32);
  float s = 0.0f;
  #pragma unroll
  for (int c = 0; c < 8; ++c) {
    const float4 v = pr[c];
    s += v.x + v.y + v.z + v.w;
  }
  rowloss[i] = __logf(s) + 20.0f - diag[i];
}

// ---------- Phase 3b: mean ----------
__global__ __launch_bounds__(1024) void final_k(
    const float* __restrict__ rowloss, float* __restrict__ out) {
  const int t = threadIdx.x;
  float s = 0.0f;
  #pragma unroll
  for (int j = 0; j < 8; ++j) s += rowloss[t + j * 1024];
  #pragma unroll
  for (int m = 1; m < 64; m <<= 1) s += __shfl_xor(s, m, 64);
  __shared__ float red[16];
  if ((t & 63) == 0) red[t >> 6] = s;
  __syncthreads();
  if (t == 0) {
    float acc = 0.0f;
    #pragma unroll
    for (int w = 0; w < 16; ++w) acc += red[w];
    out[0] = acc * (1.0f / (float)NROWS);
  }
}

extern "C" void kernel_launch(void* const* d_in, const int* in_sizes, int n_in,
                              void* d_out, int out_size, void* d_ws, size_t ws_size,
                              hipStream_t stream) {
  const float* q = (const float*)d_in[0];
  const float* p = (const float*)d_in[1];
  char* w = (char*)d_ws;
  unsigned int* qh = (unsigned int*)w;                        // 4 MB fp8
  unsigned int* ph = (unsigned int*)(w + 4194304);            // 4 MB fp8
  float* partial    = (float*)(w + 8388608);                  // 1 MB [8192][32]
  float* diag       = (float*)(w + 9437184);                  // 32 KB
  float* rowloss    = (float*)(w + 9437184 + 32768);          // 32 KB
  float* out = (float*)d_out;

  prep_k<<<NROWS, 128, 0, stream>>>(q, p, qh, ph, diag);
  gemm_lse_k<<<256, 512, 0, stream>>>(qh, ph, partial);
  rowloss_k<<<NROWS / 256, 256, 0, stream>>>(partial, diag, rowloss);
  final_k<<<1, 1024, 0, stream>>>(rowloss, out);
}

// Round 22
// 62.756 us; speedup vs baseline: 2.8529x; 1.7922x over previous
//
#include <hip/hip_runtime.h>
#include <hip/hip_bf16.h>

#define NROWS 8192
#define DIM 512
#define BM 256
#define BN 256

typedef int   i32x4 __attribute__((ext_vector_type(4)));
typedef int   i32x8 __attribute__((ext_vector_type(8)));
typedef float f32x4 __attribute__((ext_vector_type(4)));

#define FP8_SCALE_1 0x7f7f7f7f   // E8M0 127 = 2^0 in all 4 bytes

// ---------- Phase 1: normalize -> fp8, scattered into FRAGMENT-LINEAR layout ----------
// Global fragment layout (2KB lane-major blocks, one per MFMA fragment):
//  A: addr = ((((panel*4+kt)*2+wrhalf)*8+mf)*2+sel)*1024 + lane*16 + byte
//  B: addr = ((((panel*4+kt)*4+wc   )*4+nf)*2+sel)*1024 + lane*16 + byte
// where fragment spec (16x16x128 fp8): lane = l4*16+l15, row=l15 (+16*mf...),
// k = kt*128 + l4*32 + sel*16 + byte. gemm loads become base+lane*16 —
// perfectly coalesced 1024B instructions (8 full lines, the ideal).
__global__ __launch_bounds__(128) void prep_k(
    const float* __restrict__ q, const float* __restrict__ p,
    char* __restrict__ qf, char* __restrict__ pf,
    float* __restrict__ diag) {
  const int i = blockIdx.x;
  const int t = threadIdx.x;
  const int lane = t & 63, wid = t >> 6;
  const float4 qv = ((const float4*)(q + (size_t)i * DIM))[t];
  const float4 pv = ((const float4*)(p + (size_t)i * DIM))[t];
  float ssq = qv.x*qv.x + qv.y*qv.y + qv.z*qv.z + qv.w*qv.w;
  float ssp = pv.x*pv.x + pv.y*pv.y + pv.z*pv.z + pv.w*pv.w;
  float dt  = qv.x*pv.x + qv.y*pv.y + qv.z*pv.z + qv.w*pv.w;
  #pragma unroll
  for (int m = 1; m < 64; m <<= 1) {
    ssq += __shfl_xor(ssq, m, 64);
    ssp += __shfl_xor(ssp, m, 64);
    dt  += __shfl_xor(dt,  m, 64);
  }
  __shared__ float red[3][2];
  if (lane == 0) { red[0][wid] = ssq; red[1][wid] = ssp; red[2][wid] = dt; }
  __syncthreads();
  ssq = red[0][0] + red[0][1];
  ssp = red[1][0] + red[1][1];
  dt  = red[2][0] + red[2][1];
  const float invq = 1.0f / fmaxf(sqrtf(ssq), 1e-8f);
  const float invp = 1.0f / fmaxf(sqrtf(ssp), 1e-8f);
  int rq = 0, rp = 0;
  rq = __builtin_amdgcn_cvt_pk_fp8_f32(qv.x * invq, qv.y * invq, rq, false);
  rq = __builtin_amdgcn_cvt_pk_fp8_f32(qv.z * invq, qv.w * invq, rq, true);
  rp = __builtin_amdgcn_cvt_pk_fp8_f32(pv.x * invp, pv.y * invp, rp, false);
  rp = __builtin_amdgcn_cvt_pk_fp8_f32(pv.z * invp, pv.w * invp, rp, true);

  // scatter: k = t*4
  const int panel = i >> 8, lr = i & 255;
  const int kt  = t >> 5;              // (t*4) >> 7
  const int l4g = (t >> 3) & 3;        // ((t*4)&127) >> 5
  const int sel = (t >> 2) & 1;        // ((t*4)&31) >> 4
  const int byo = (t & 3) * 4;         // (t*4) & 15
  const int laneT = l4g * 16 + (lr & 15);
  const size_t addrA =
      ((((size_t)(panel * 4 + kt) * 2 + (lr >> 7)) * 8 + ((lr >> 4) & 7)) * 2 + sel) * 1024
      + laneT * 16 + byo;
  const size_t addrB =
      ((((size_t)(panel * 4 + kt) * 4 + (lr >> 6)) * 4 + ((lr >> 4) & 3)) * 2 + sel) * 1024
      + laneT * 16 + byo;
  *(unsigned int*)(qf + addrA) = (unsigned int)rq;
  *(unsigned int*)(pf + addrB) = (unsigned int)rp;
  if (t == 0) diag[i] = dt * invq * invp * 20.0f;
}

// ---------- Phase 2: MX-fp8 GEMM, fragment-linear DIRECT loads, ZERO K-loop barriers ----------
// 256 persistent blocks (1/CU), 8 waves (2Mx4N), 128x64 out/wave, transposed
// accumulators. No LDS operands, no staging, no K-loop barriers: waves fully
// desynchronized; compiler emits counted vmcnt per dependency; loads of the
// next iter issue under the current MFMA drain (in-order pipelining for free).
// L2-resident panel map (r13-proven, FETCH 12.6MB): XCD g owns 8 A-panels
// (1MB) + 16 B-panels (2MB) = 3MB < 4MB L2. Every load: base + lane*16 —
// 1024B fully-coalesced (fixes r21's 16-line-split, the measured wall).
__global__ __launch_bounds__(512, 2) void gemm_lse_k(
    const char* __restrict__ qf, const char* __restrict__ pf,
    float* __restrict__ partial) {
  __shared__ float psum[1024];                  // only LDS: 4KB flush buffer
  const int tid = threadIdx.x;
  const int lane = tid & 63, wid = tid >> 6;
  const int wr = wid >> 2, wc = wid & 3;        // 2M x 4N wave grid
  const int l15 = lane & 15, l4 = lane >> 4;
  const int b = blockIdx.x;
  const int g = b & 7;                          // XCD (round-robin dispatch)
  const int j = b >> 3;                         // 0..31 within XCD
  const int panelA = (g & 3) * 8 + (j & 7);     // A panel (4 blocks share)
  const int bnset  = (g >> 2) * 16 + (j >> 3) * 4;   // 4 B panels (8 share)
  const int bm = panelA * BM;
  // per-lane linear offset inside every 2KB fragment block
  const char* aPanel = qf + (size_t)panelA * 131072 + (size_t)lane * 16;
  const char* pBase  = pf + (size_t)lane * 16;

  f32x4 acc[4][8] = {};                         // [nb][am], transposed
  i32x8 af[8], bf[4];

  #pragma unroll 1
  for (int tt = 0; tt < 16; ++tt) {
    const int kt = tt & 3, t = tt >> 2;
    const char* aB = aPanel + (size_t)(kt * 2 + wr) * 16384;
    const char* bB = pBase +
        (size_t)(((bnset + t) * 4 + kt) * 4 + wc) * 8192;

    // 24 fully-coalesced 1024B loads (12 frags x lo/hi)
    #pragma unroll
    for (int mf = 0; mf < 8; ++mf) {
      const i32x4 lo = *(const i32x4*)(aB + mf * 2048);
      const i32x4 hi = *(const i32x4*)(aB + mf * 2048 + 1024);
      af[mf] = __builtin_shufflevector(lo, hi, 0, 1, 2, 3, 4, 5, 6, 7);
    }
    #pragma unroll
    for (int nf = 0; nf < 4; ++nf) {
      const i32x4 lo = *(const i32x4*)(bB + nf * 2048);
      const i32x4 hi = *(const i32x4*)(bB + nf * 2048 + 1024);
      bf[nf] = __builtin_shufflevector(lo, hi, 0, 1, 2, 3, 4, 5, 6, 7);
    }

    __builtin_amdgcn_s_setprio(1);
    #pragma unroll
    for (int nb = 0; nb < 4; ++nb)
      #pragma unroll
      for (int am = 0; am < 8; ++am)
        acc[nb][am] = __builtin_amdgcn_mfma_scale_f32_16x16x128_f8f6f4(
            bf[nb], af[am], acc[nb][am], 0, 0, 0, FP8_SCALE_1, 0, FP8_SCALE_1);
    __builtin_amdgcn_s_setprio(0);

    if ((tt & 3) == 3) {
      // ---- flush output tile t: exp(20c-20) + row-sum + store ----
      // Lane rows m = wr*128 + am*16 + l15; cols n = wc*64 + nb*16 + l4*4 + r.
      const int bxc = bnset + t;
      #pragma unroll
      for (int am = 0; am < 8; ++am) {
        float s = 0.0f;
        #pragma unroll
        for (int nb = 0; nb < 4; ++nb)
          #pragma unroll
          for (int r = 0; r < 4; ++r)
            s += __expf(acc[nb][am][r] * 20.0f - 20.0f);
        s += __shfl_xor(s, 16, 64);
        s += __shfl_xor(s, 32, 64);
        if (l4 == 0)
          psum[wc * 256 + wr * 128 + am * 16 + l15] = s;
      }
      __syncthreads();
      if (tid < 256)
        partial[(size_t)(bm + tid) * 32 + bxc] =
            psum[tid] + psum[256 + tid] + psum[512 + tid] + psum[768 + tid];
      __syncthreads();      // psum safe before next tile's writes
      #pragma unroll
      for (int nb = 0; nb < 4; ++nb)
        #pragma unroll
        for (int am = 0; am < 8; ++am)
          acc[nb][am] = f32x4{0.0f, 0.0f, 0.0f, 0.0f};
    }
  }
}

// ---------- Phase 3a: per-row loss ----------
__global__ __launch_bounds__(256) void rowloss_k(
    const float* __restrict__ partial, const float* __restrict__ diag,
    float* __restrict__ rowloss) {
  const int i = blockIdx.x * 256 + threadIdx.x;
  const float4* pr = (const float4*)(partial + (size_t)i * 32);
  float s = 0.0f;
  #pragma unroll
  for (int c = 0; c < 8; ++c) {
    const float4 v = pr[c];
    s += v.x + v.y + v.z + v.w;
  }
  rowloss[i] = __logf(s) + 20.0f - diag[i];
}

// ---------- Phase 3b: mean ----------
__global__ __launch_bounds__(1024) void final_k(
    const float* __restrict__ rowloss, float* __restrict__ out) {
  const int t = threadIdx.x;
  float s = 0.0f;
  #pragma unroll
  for (int j = 0; j < 8; ++j) s += rowloss[t + j * 1024];
  #pragma unroll
  for (int m = 1; m < 64; m <<= 1) s += __shfl_xor(s, m, 64);
  __shared__ float red[16];
  if ((t & 63) == 0) red[t >> 6] = s;
  __syncthreads();
  if (t == 0) {
    float acc = 0.0f;
    #pragma unroll
    for (int w = 0; w < 16; ++w) acc += red[w];
    out[0] = acc * (1.0f / (float)NROWS);
  }
}

extern "C" void kernel_launch(void* const* d_in, const int* in_sizes, int n_in,
                              void* d_out, int out_size, void* d_ws, size_t ws_size,
                              hipStream_t stream) {
  const float* q = (const float*)d_in[0];
  const float* p = (const float*)d_in[1];
  char* w = (char*)d_ws;
  char* qf = w;                                               // 4 MB fp8 frags
  char* pf = w + 4194304;                                     // 4 MB fp8 frags
  float* partial    = (float*)(w + 8388608);                  // 1 MB [8192][32]
  float* diag       = (float*)(w + 9437184);                  // 32 KB
  float* rowloss    = (float*)(w + 9437184 + 32768);          // 32 KB
  float* out = (float*)d_out;

  prep_k<<<NROWS, 128, 0, stream>>>(q, p, qf, pf, diag);
  gemm_lse_k<<<256, 512, 0, stream>>>(qf, pf, partial);
  rowloss_k<<<NROWS / 256, 256, 0, stream>>>(partial, diag, rowloss);
  final_k<<<1, 1024, 0, stream>>>(rowloss, out);
}

// Round 23
// 58.178 us; speedup vs baseline: 3.0774x; 1.0787x over previous
//
#include <hip/hip_runtime.h>
#include <hip/hip_bf16.h>

#define NROWS 8192
#define DIM 512
#define BM 256
#define BN 256

typedef int   i32x4 __attribute__((ext_vector_type(4)));
typedef int   i32x8 __attribute__((ext_vector_type(8)));
typedef float f32x4 __attribute__((ext_vector_type(4)));

#define FP8_SCALE_1 0x7f7f7f7f   // E8M0 127 = 2^0 in all 4 bytes

// ---------- Phase 1: normalize -> fp8 -> FRAGMENT-LINEAR layout, coalesced ----------
// Output layout (byte-identical to r22, verified absmax 0.0):
//  A: ((((panel*4+kt)*2+wrhalf)*8+mf)*2+sel)*1024 + laneT*16 + byte
//  B: ((((panel*4+kt)*4+wc   )*4+nf)*2+sel)*1024 + laneT*16 + byte
// 512 blocks x 256 thr; block owns 16 rows (one fragment row-group: fixed
// wrhalf/mf resp. wc/nf). Reads unit-stride float4; fp8 staged in padded LDS
// (row stride 528B -> <=4-way); writes full 1024B fragment blocks coalesced.
__global__ __launch_bounds__(256) void prep_k(
    const float* __restrict__ q, const float* __restrict__ p,
    char* __restrict__ qf, char* __restrict__ pf,
    float* __restrict__ diag) {
  __shared__ char ldsq[16 * 528];
  __shared__ char ldsp[16 * 528];
  const int tid = threadIdx.x;
  const int blk = blockIdx.x;
  const int rr = tid >> 4;              // row in group
  const int cs = tid & 15;              // 16 threads per row
  const int i  = blk * 16 + rr;         // global row
  const float4* qr = (const float4*)(q + (size_t)i * DIM);
  const float4* pr = (const float4*)(p + (size_t)i * DIM);

  float4 qv[8], pv[8];
  float ssq = 0.0f, ssp = 0.0f, dt = 0.0f;
  #pragma unroll
  for (int jj = 0; jj < 8; ++jj) {
    qv[jj] = qr[jj * 16 + cs];          // unit-stride across 16 lanes
    pv[jj] = pr[jj * 16 + cs];
    ssq += qv[jj].x*qv[jj].x + qv[jj].y*qv[jj].y + qv[jj].z*qv[jj].z + qv[jj].w*qv[jj].w;
    ssp += pv[jj].x*pv[jj].x + pv[jj].y*pv[jj].y + pv[jj].z*pv[jj].z + pv[jj].w*pv[jj].w;
    dt  += qv[jj].x*pv[jj].x + qv[jj].y*pv[jj].y + qv[jj].z*pv[jj].z + qv[jj].w*pv[jj].w;
  }
  // 16-lane butterfly (rows own contiguous 16-lane groups)
  #pragma unroll
  for (int m = 1; m < 16; m <<= 1) {
    ssq += __shfl_xor(ssq, m, 64);
    ssp += __shfl_xor(ssp, m, 64);
    dt  += __shfl_xor(dt,  m, 64);
  }
  const float invq = 1.0f / fmaxf(sqrtf(ssq), 1e-8f);
  const float invp = 1.0f / fmaxf(sqrtf(ssp), 1e-8f);
  if (cs == 0) diag[i] = dt * invq * invp * 20.0f;

  #pragma unroll
  for (int jj = 0; jj < 8; ++jj) {
    int rq = 0, rp = 0;
    rq = __builtin_amdgcn_cvt_pk_fp8_f32(qv[jj].x * invq, qv[jj].y * invq, rq, false);
    rq = __builtin_amdgcn_cvt_pk_fp8_f32(qv[jj].z * invq, qv[jj].w * invq, rq, true);
    rp = __builtin_amdgcn_cvt_pk_fp8_f32(pv[jj].x * invp, pv[jj].y * invp, rp, false);
    rp = __builtin_amdgcn_cvt_pk_fp8_f32(pv[jj].z * invp, pv[jj].w * invp, rp, true);
    *(unsigned int*)(ldsq + rr * 528 + jj * 64 + cs * 4) = (unsigned int)rq;
    *(unsigned int*)(ldsp + rr * 528 + jj * 64 + cs * 4) = (unsigned int)rp;
  }
  __syncthreads();

  // coalesced fragment-block writes: 512 x 16B chunks (4kt x 2sel x 64laneT)
  const int panel = blk >> 4, rg = blk & 15;
  #pragma unroll
  for (int u = 0; u < 2; ++u) {
    const int o = 2 * tid + u;
    const int kt = o >> 7, sel = (o >> 6) & 1, laneT = o & 63;
    const int rrs = laneT & 15;
    const int srcoff = kt * 128 + (laneT >> 4) * 32 + sel * 16;
    const i32x4 va = *(const i32x4*)(ldsq + rrs * 528 + srcoff);
    const size_t aaddr =
        ((((size_t)(panel * 4 + kt) * 2 + (rg >> 3)) * 8 + (rg & 7)) * 2 + sel) * 1024
        + laneT * 16;
    *(i32x4*)(qf + aaddr) = va;
    const i32x4 vb = *(const i32x4*)(ldsp + rrs * 528 + srcoff);
    const size_t baddr =
        ((((size_t)(panel * 4 + kt) * 4 + (rg >> 2)) * 4 + (rg & 3)) * 2 + sel) * 1024
        + laneT * 16;
    *(i32x4*)(pf + baddr) = vb;
  }
}

// ---------- Phase 2: MX-fp8 GEMM, fragment-linear direct loads, 4 waves/SIMD ----------
// r22's gemm (45.7us, matched LDS champion with zero LDS/barriers) with grid
// 512 = 2 independent blocks/CU: the direct-global design has NO LDS-read
// amplification (r19's failure mode), so cross-block overlap is clean. Each
// SIMD hosts 4 waves from 2 barrier-free blocks -> per-wave L2 load-wait
// phases (the measured wall: MfmaUtil 28%, pipes idle) hide under other
// waves' MFMA bursts. Same L2-resident map: XCD g owns 8 A-panels + 16
// B-panels = 3MB < 4MB L2; co-resident block pairs share their A panel.
__global__ __launch_bounds__(512, 2) void gemm_lse_k(
    const char* __restrict__ qf, const char* __restrict__ pf,
    float* __restrict__ partial) {
  __shared__ float psum[1024];                  // only LDS: 4KB flush buffer
  const int tid = threadIdx.x;
  const int lane = tid & 63, wid = tid >> 6;
  const int wr = wid >> 2, wc = wid & 3;        // 2M x 4N wave grid
  const int l15 = lane & 15, l4 = lane >> 4;
  const int b = blockIdx.x;
  const int g = b & 7;                          // XCD (round-robin dispatch)
  const int j = b >> 3;                         // 0..63 within XCD
  const int panelA = (g & 3) * 8 + (j & 7);     // A panel (8 blocks share)
  const int bnset  = (g >> 2) * 16 + (j >> 3) * 2;   // 2 B panels (8 share)
  const int bm = panelA * BM;
  const char* aPanel = qf + (size_t)panelA * 131072 + (size_t)lane * 16;
  const char* pBase  = pf + (size_t)lane * 16;

  f32x4 acc[4][8] = {};                         // [nb][am], transposed
  i32x8 af[8], bf[4];

  #pragma unroll 1
  for (int tt = 0; tt < 8; ++tt) {
    const int kt = tt & 3, t = tt >> 2;
    const char* aB = aPanel + (size_t)(kt * 2 + wr) * 16384;
    const char* bB = pBase +
        (size_t)(((bnset + t) * 4 + kt) * 4 + wc) * 8192;

    // 24 fully-coalesced 1024B loads (12 frags x lo/hi)
    #pragma unroll
    for (int mf = 0; mf < 8; ++mf) {
      const i32x4 lo = *(const i32x4*)(aB + mf * 2048);
      const i32x4 hi = *(const i32x4*)(aB + mf * 2048 + 1024);
      af[mf] = __builtin_shufflevector(lo, hi, 0, 1, 2, 3, 4, 5, 6, 7);
    }
    #pragma unroll
    for (int nf = 0; nf < 4; ++nf) {
      const i32x4 lo = *(const i32x4*)(bB + nf * 2048);
      const i32x4 hi = *(const i32x4*)(bB + nf * 2048 + 1024);
      bf[nf] = __builtin_shufflevector(lo, hi, 0, 1, 2, 3, 4, 5, 6, 7);
    }

    __builtin_amdgcn_s_setprio(1);
    #pragma unroll
    for (int nb = 0; nb < 4; ++nb)
      #pragma unroll
      for (int am = 0; am < 8; ++am)
        acc[nb][am] = __builtin_amdgcn_mfma_scale_f32_16x16x128_f8f6f4(
            bf[nb], af[am], acc[nb][am], 0, 0, 0, FP8_SCALE_1, 0, FP8_SCALE_1);
    __builtin_amdgcn_s_setprio(0);

    if ((tt & 3) == 3) {
      // ---- flush output tile t: exp(20c-20) + row-sum + store ----
      // Lane rows m = wr*128 + am*16 + l15; cols n = wc*64 + nb*16 + l4*4 + r.
      const int bxc = bnset + t;
      #pragma unroll
      for (int am = 0; am < 8; ++am) {
        float s = 0.0f;
        #pragma unroll
        for (int nb = 0; nb < 4; ++nb)
          #pragma unroll
          for (int r = 0; r < 4; ++r)
            s += __expf(acc[nb][am][r] * 20.0f - 20.0f);
        s += __shfl_xor(s, 16, 64);
        s += __shfl_xor(s, 32, 64);
        if (l4 == 0)
          psum[wc * 256 + wr * 128 + am * 16 + l15] = s;
      }
      __syncthreads();
      if (tid < 256)
        partial[(size_t)(bm + tid) * 32 + bxc] =
            psum[tid] + psum[256 + tid] + psum[512 + tid] + psum[768 + tid];
      __syncthreads();      // psum safe before next tile's writes
      #pragma unroll
      for (int nb = 0; nb < 4; ++nb)
        #pragma unroll
        for (int am = 0; am < 8; ++am)
          acc[nb][am] = f32x4{0.0f, 0.0f, 0.0f, 0.0f};
    }
  }
}

// ---------- Phase 3a: per-row loss ----------
__global__ __launch_bounds__(256) void rowloss_k(
    const float* __restrict__ partial, const float* __restrict__ diag,
    float* __restrict__ rowloss) {
  const int i = blockIdx.x * 256 + threadIdx.x;
  const float4* pr = (const float4*)(partial + (size_t)i * 32);
  float s = 0.0f;
  #pragma unroll
  for (int c = 0; c < 8; ++c) {
    const float4 v = pr[c];
    s += v.x + v.y + v.z + v.w;
  }
  rowloss[i] = __logf(s) + 20.0f - diag[i];
}

// ---------- Phase 3b: mean ----------
__global__ __launch_bounds__(1024) void final_k(
    const float* __restrict__ rowloss, float* __restrict__ out) {
  const int t = threadIdx.x;
  float s = 0.0f;
  #pragma unroll
  for (int j = 0; j < 8; ++j) s += rowloss[t + j * 1024];
  #pragma unroll
  for (int m = 1; m < 64; m <<= 1) s += __shfl_xor(s, m, 64);
  __shared__ float red[16];
  if ((t & 63) == 0) red[t >> 6] = s;
  __syncthreads();
  if (t == 0) {
    float acc = 0.0f;
    #pragma unroll
    for (int w = 0; w < 16; ++w) acc += red[w];
    out[0] = acc * (1.0f / (float)NROWS);
  }
}

extern "C" void kernel_launch(void* const* d_in, const int* in_sizes, int n_in,
                              void* d_out, int out_size, void* d_ws, size_t ws_size,
                              hipStream_t stream) {
  const float* q = (const float*)d_in[0];
  const float* p = (const float*)d_in[1];
  char* w = (char*)d_ws;
  char* qf = w;                                               // 4 MB fp8 frags
  char* pf = w + 4194304;                                     // 4 MB fp8 frags
  float* partial    = (float*)(w + 8388608);                  // 1 MB [8192][32]
  float* diag       = (float*)(w + 9437184);                  // 32 KB
  float* rowloss    = (float*)(w + 9437184 + 32768);          // 32 KB
  float* out = (float*)d_out;

  prep_k<<<NROWS / 16, 256, 0, stream>>>(q, p, qf, pf, diag);
  gemm_lse_k<<<512, 512, 0, stream>>>(qf, pf, partial);
  rowloss_k<<<NROWS / 256, 256, 0, stream>>>(partial, diag, rowloss);
  final_k<<<1, 1024, 0, stream>>>(rowloss, out);
}